// Round 3
// baseline (1150.542 us; speedup 1.0000x reference)
//
#include <hip/hip_runtime.h>
#include <math.h>

#define NB 8
#define NG 4
#define HID 128
#define NPTS 1331
#define NPAD 1344          // 21 * 64
#define NT 21
#define EPS 1e-6f

// ---------------- compile-time Clifford algebra tables ----------------
struct Alg {
  int grade[NB];
  signed char gp_j[NB][NB]; float gp_s[NB][NB]; signed char gp_p[NB][NB]; // gprod (i,k)->(j,sign,path)
  signed char ks_k[NB][NB]; float ks_s[NB][NB]; signed char ks_p[NB][NB]; // expand (l,m)->(k*,sign,path)
};

constexpr int popc3(int x){ return (x&1)+((x>>1)&1)+((x>>2)&1); }

constexpr Alg build_alg(){
  Alg A{};
  int order[NB]{}; int idx[NB]{};
  int t=0;
  for(int g=0; g<=3; ++g) for(int b=0;b<NB;++b) if(popc3(b)==g) order[t++]=b;
  for(int i=0;i<NB;++i) idx[order[i]]=i;
  for(int i=0;i<NB;++i) A.grade[i]=popc3(order[i]);
  float C[NB][NB][NB]{};
  for(int a=0;a<NB;++a) for(int b=0;b<NB;++b){
    int s=0, tt=a>>1;
    while(tt){ s += popc3(tt&b); tt>>=1; }
    C[idx[a]][idx[b]][idx[a^b]] = (s&1)?-1.0f:1.0f;
  }
  bool paths[NG][NG][NG]{};
  for(int i=0;i<NB;++i)for(int j=0;j<NB;++j)for(int k=0;k<NB;++k)
    if(C[i][j][k]!=0.0f) paths[A.grade[i]][A.grade[j]][A.grade[k]]=true;
  int pid[NG][NG][NG]{};
  int p=0;
  for(int a=0;a<NG;++a)for(int b=0;b<NG;++b)for(int c=0;c<NG;++c)
    if(paths[a][b][c]) pid[a][b][c]=p++;
  for(int i=0;i<NB;++i)for(int k=0;k<NB;++k){
    int j = idx[order[i]^order[k]];
    A.gp_j[i][k]=(signed char)j;
    A.gp_s[i][k]=C[i][k][j];
    A.gp_p[i][k]=(signed char)pid[A.grade[i]][A.grade[k]][A.grade[j]];
  }
  for(int l=0;l<NB;++l)for(int m=0;m<NB;++m){
    int k = idx[order[l]^order[m]];
    A.ks_k[l][m]=(signed char)k;
    A.ks_s[l][m]=C[k][m][l];
    A.ks_p[l][m]=(signed char)pid[A.grade[k]][A.grade[m]][A.grade[l]];
  }
  return A;
}

__device__ const Alg ALG = build_alg();

__device__ __forceinline__ float sigm(float x){ return 1.f/(1.f+expf(-x)); }

// ---------------- K0: grid + conditioning -> h0 [8][128][NPAD] (ch 0..32) ----
__global__ __launch_bounds__(256) void k_prep(
    const float* __restrict__ condition,  // [32][8]
    const float* __restrict__ sigma1,     // [1]
    const float* __restrict__ cond_a,     // [32][4]
    const float* __restrict__ cond_w,     // [4][128]
    const float* __restrict__ cond_b,     // [128]
    float* __restrict__ norm2_o,          // [NPAD]
    float* __restrict__ h0)               // [8][128][NPAD]
{
  const int n = blockIdx.x*256 + threadIdx.x;
  if (n >= NPAD) return;
  const bool act = (n < NPTS);
  float px=0.f, py=0.f, pz=0.f, nr=0.f, sc=0.f;
  if (act){
    int i0 = n/121; int r = n - i0*121; int i1 = r/11; int i2 = r - i1*11;
    px = (float)(-1.0 + 0.2*(double)i0);
    py = (float)(-1.0 + 0.2*(double)i1);
    pz = (float)(-1.0 + 0.2*(double)i2);
    nr = px*px + py*py + pz*pz;
    float s = sigma1[0];
    sc = expf(-nr/(2.f*s*s));
  }
  norm2_o[n] = nr;
  // channel 0: the x multivector (scalar, vector part)
  h0[(0*HID+0)*NPAD+n] = sc;
  h0[(1*HID+0)*NPAD+n] = px;
  h0[(2*HID+0)*NPAD+n] = py;
  h0[(3*HID+0)*NPAD+n] = pz;
  h0[(4*HID+0)*NPAD+n] = 0.f;
  h0[(5*HID+0)*NPAD+n] = 0.f;
  h0[(6*HID+0)*NPAD+n] = 0.f;
  h0[(7*HID+0)*NPAD+n] = 0.f;
  const float rn0 = sqrtf(sc*sc + EPS);
  const float rn1 = sqrtf(nr + EPS);
  const float rn2 = sqrtf(EPS);
  const float rn3 = sqrtf(EPS);
  for (int c=0;c<32;++c){
    float cb[NB];
    #pragma unroll
    for (int b=0;b<NB;++b) cb[b] = condition[c*8+b];
    float gn2[4];
    gn2[0] = cb[0]*cb[0] + EPS;
    gn2[1] = cb[1]*cb[1] + cb[2]*cb[2] + cb[3]*cb[3] + EPS;
    gn2[2] = cb[4]*cb[4] + cb[5]*cb[5] + cb[6]*cb[6] + EPS;
    gn2[3] = cb[7]*cb[7] + EPS;
    float fac[4];
    #pragma unroll
    for (int g=0; g<4; ++g){
      const float gn = sqrtf(gn2[g]);
      const float den = fmaf(sigm(cond_a[c*4+g]), gn-1.f, 1.f);
      float scl = cond_b[c*4+g];
      scl = fmaf(rn0, cond_w[0*128 + c*4+g], scl);
      scl = fmaf(rn1, cond_w[1*128 + c*4+g], scl);
      scl = fmaf(rn2, cond_w[2*128 + c*4+g], scl);
      scl = fmaf(rn3, cond_w[3*128 + c*4+g], scl);
      fac[g] = (1.f + scl)/den;
    }
    h0[(0*HID + c+1)*NPAD + n] = act ? cb[0]*fac[0] : 0.f;
    h0[(1*HID + c+1)*NPAD + n] = act ? cb[1]*fac[1] : 0.f;
    h0[(2*HID + c+1)*NPAD + n] = act ? cb[2]*fac[1] : 0.f;
    h0[(3*HID + c+1)*NPAD + n] = act ? cb[3]*fac[1] : 0.f;
    h0[(4*HID + c+1)*NPAD + n] = act ? cb[4]*fac[2] : 0.f;
    h0[(5*HID + c+1)*NPAD + n] = act ? cb[5]*fac[2] : 0.f;
    h0[(6*HID + c+1)*NPAD + n] = act ? cb[6]*fac[2] : 0.f;
    h0[(7*HID + c+1)*NPAD + n] = act ? cb[7]*fac[3] : 0.f;
  }
}

// ---------------- KA: h' = mvsilu(mvlinear(h, W)) ----------------
// h layout [8][128][NPAD]; block: 64 n-lanes x 4 waves, 8 out-ch per thread.
template<int KIN>
__global__ __launch_bounds__(256) void k_lin_silu(
    const float* __restrict__ hin, const float* __restrict__ W, // [128][KIN][4]
    const float* __restrict__ sa, const float* __restrict__ sb, // [128][4]
    float* __restrict__ hout)
{
  const int lane = threadIdx.x & 63;
  const int wv   = threadIdx.x >> 6;
  const int n    = blockIdx.x * 64 + lane;
  const int o0   = blockIdx.y * 32 + wv * 8;
  float acc[8][NB];
  #pragma unroll
  for (int j=0;j<8;++j)
    #pragma unroll
    for (int b=0;b<NB;++b) acc[j][b]=0.f;

  for (int i=0;i<KIN;++i){
    float hv[NB];
    #pragma unroll
    for (int b=0;b<NB;++b) hv[b] = hin[(b*HID+i)*NPAD + n];
    #pragma unroll
    for (int j=0;j<8;++j){
      const float4 w = *reinterpret_cast<const float4*>(W + ((size_t)(o0+j)*KIN + i)*4);
      acc[j][0] = fmaf(hv[0], w.x, acc[j][0]);
      acc[j][1] = fmaf(hv[1], w.y, acc[j][1]);
      acc[j][2] = fmaf(hv[2], w.y, acc[j][2]);
      acc[j][3] = fmaf(hv[3], w.y, acc[j][3]);
      acc[j][4] = fmaf(hv[4], w.z, acc[j][4]);
      acc[j][5] = fmaf(hv[5], w.z, acc[j][5]);
      acc[j][6] = fmaf(hv[6], w.z, acc[j][6]);
      acc[j][7] = fmaf(hv[7], w.w, acc[j][7]);
    }
  }
  #pragma unroll
  for (int j=0;j<8;++j){
    const int o = o0+j;
    const float g0 = sqrtf(acc[j][0]*acc[j][0] + EPS);
    const float g1 = sqrtf(acc[j][1]*acc[j][1] + acc[j][2]*acc[j][2] + acc[j][3]*acc[j][3] + EPS);
    const float g2 = sqrtf(acc[j][4]*acc[j][4] + acc[j][5]*acc[j][5] + acc[j][6]*acc[j][6] + EPS);
    const float g3 = sqrtf(acc[j][7]*acc[j][7] + EPS);
    const float t0 = sigm(fmaf(sa[o*4+0], g0, sb[o*4+0]));
    const float t1 = sigm(fmaf(sa[o*4+1], g1, sb[o*4+1]));
    const float t2 = sigm(fmaf(sa[o*4+2], g2, sb[o*4+2]));
    const float t3 = sigm(fmaf(sa[o*4+3], g3, sb[o*4+3]));
    hout[(0*HID+o)*NPAD+n] = acc[j][0]*t0;
    hout[(1*HID+o)*NPAD+n] = acc[j][1]*t1;
    hout[(2*HID+o)*NPAD+n] = acc[j][2]*t1;
    hout[(3*HID+o)*NPAD+n] = acc[j][3]*t1;
    hout[(4*HID+o)*NPAD+n] = acc[j][4]*t2;
    hout[(5*HID+o)*NPAD+n] = acc[j][5]*t2;
    hout[(6*HID+o)*NPAD+n] = acc[j][6]*t2;
    hout[(7*HID+o)*NPAD+n] = acc[j][7]*t3;
  }
}

// ---------------- KB: q = mvlinear(h, Q); h_next = gprod(h, q, gw) ----------
__global__ __launch_bounds__(256) void k_q_gprod(
    const float* __restrict__ hin, const float* __restrict__ Q,  // [128][128][4]
    const float* __restrict__ gw,                                // [128][20]
    float* __restrict__ hout)
{
  const int lane = threadIdx.x & 63;
  const int wv   = threadIdx.x >> 6;
  const int n    = blockIdx.x * 64 + lane;
  const int c0   = blockIdx.y * 32 + wv * 8;
  float q[8][NB];
  #pragma unroll
  for (int j=0;j<8;++j)
    #pragma unroll
    for (int b=0;b<NB;++b) q[j][b]=0.f;

  for (int i=0;i<HID;++i){
    float hv[NB];
    #pragma unroll
    for (int b=0;b<NB;++b) hv[b] = hin[(b*HID+i)*NPAD + n];
    #pragma unroll
    for (int j=0;j<8;++j){
      const float4 w = *reinterpret_cast<const float4*>(Q + ((size_t)(c0+j)*HID + i)*4);
      q[j][0] = fmaf(hv[0], w.x, q[j][0]);
      q[j][1] = fmaf(hv[1], w.y, q[j][1]);
      q[j][2] = fmaf(hv[2], w.y, q[j][2]);
      q[j][3] = fmaf(hv[3], w.y, q[j][3]);
      q[j][4] = fmaf(hv[4], w.z, q[j][4]);
      q[j][5] = fmaf(hv[5], w.z, q[j][5]);
      q[j][6] = fmaf(hv[6], w.z, q[j][6]);
      q[j][7] = fmaf(hv[7], w.w, q[j][7]);
    }
  }
  #pragma unroll
  for (int j=0;j<8;++j){
    const int c = c0+j;
    float xv[NB];
    #pragma unroll
    for (int b=0;b<NB;++b) xv[b] = hin[(b*HID+c)*NPAD + n];
    float wp[20];
    #pragma unroll
    for (int p=0;p<20;++p) wp[p] = gw[c*20+p];
    float ov[NB] = {0.f,0.f,0.f,0.f,0.f,0.f,0.f,0.f};
    #pragma unroll
    for (int i=0;i<NB;++i)
      #pragma unroll
      for (int k=0;k<NB;++k){
        const int J = ALG.gp_j[i][k];
        const int P = ALG.gp_p[i][k];
        const float t = xv[i]*q[j][k];
        ov[J] = fmaf(ALG.gp_s[i][k] > 0.f ? t : -t, wp[P], ov[J]);
      }
    #pragma unroll
    for (int b=0;b<NB;++b) hout[(b*HID+c)*NPAD+n] = ov[b];
  }
}

// ---------------- KF: final mvlinear + shell + Cayley expansion --------------
__global__ __launch_bounds__(256) void k_final(
    const float* __restrict__ hin,   // [8][128][NPAD]
    const float* __restrict__ fw,    // [1024][128][4]
    const float* __restrict__ ss,    // [1024][8]
    const float* __restrict__ cw,    // [32][32][20]
    const float* __restrict__ norm2, // [NPAD]
    float* __restrict__ out)         // [256][256][1331]
{
  __shared__ float lds[256*64];      // [8 blades][32 ch][64 n] = 64 KiB
  const int lane = threadIdx.x & 63;
  const int wv   = threadIdx.x >> 6;
  const int nb   = blockIdx.x;                 // 0..20
  const int n    = nb*64 + lane;
  const int oi0  = blockIdx.y * 16 + wv * 4;   // 4 oi per thread
  float acc[4][NB];
  #pragma unroll
  for (int j=0;j<4;++j)
    #pragma unroll
    for (int b=0;b<NB;++b) acc[j][b]=0.f;

  for (int ci=0; ci<HID; ci+=32){
    __syncthreads();
    #pragma unroll
    for (int rep=0; rep<16; ++rep){
      const int e   = rep*256 + threadIdx.x;   // float4 id, 4096 total
      const int row = e >> 4;                  // (b*32 + cc)
      const int c4  = e & 15;
      const int b   = row >> 5;
      const int cc  = row & 31;
      const float4 v = *reinterpret_cast<const float4*>(hin + (size_t)(b*HID + ci + cc)*NPAD + nb*64 + c4*4);
      *reinterpret_cast<float4*>(&lds[row*64 + c4*4]) = v;
    }
    __syncthreads();
    for (int cc=0; cc<32; ++cc){
      float hv[NB];
      #pragma unroll
      for (int b=0;b<NB;++b) hv[b] = lds[(b*32+cc)*64 + lane];
      #pragma unroll
      for (int j=0;j<4;++j){
        const float4 w = *reinterpret_cast<const float4*>(fw + ((size_t)(oi0+j)*HID + ci+cc)*4);
        acc[j][0] = fmaf(hv[0], w.x, acc[j][0]);
        acc[j][1] = fmaf(hv[1], w.y, acc[j][1]);
        acc[j][2] = fmaf(hv[2], w.y, acc[j][2]);
        acc[j][3] = fmaf(hv[3], w.y, acc[j][3]);
        acc[j][4] = fmaf(hv[4], w.z, acc[j][4]);
        acc[j][5] = fmaf(hv[5], w.z, acc[j][5]);
        acc[j][6] = fmaf(hv[6], w.z, acc[j][6]);
        acc[j][7] = fmaf(hv[7], w.w, acc[j][7]);
      }
    }
  }

  const float INVS = (float)(1.0 / sqrt((double)NPTS));
  const float nr   = norm2[n];
  const bool  act  = (n < NPTS);
  #pragma unroll
  for (int j=0;j<4;++j){
    const int oi = oi0+j;
    const int o  = oi >> 5;
    const int i  = oi & 31;
    float kf[NB];
    #pragma unroll
    for (int b=0;b<NB;++b){
      const float s = ss[oi*8+b];
      kf[b] = acc[j][b] * expf(-nr/(2.f*s*s)) * INVS;
    }
    float wp[20];
    #pragma unroll
    for (int p=0;p<20;++p) wp[p] = cw[oi*20+p];
    float* obase = out + (size_t)(o*2048 + i*8)*NPTS + n;
    if (act){
      #pragma unroll
      for (int l=0;l<NB;++l)
        #pragma unroll
        for (int m=0;m<NB;++m){
          const float t = kf[ALG.ks_k[l][m]] * wp[ALG.ks_p[l][m]];
          obase[(size_t)(l*256+m)*NPTS] = (ALG.ks_s[l][m] > 0.f) ? t : -t;
        }
    }
  }
}

// ---------------- launch ----------------
extern "C" void kernel_launch(void* const* d_in, const int* in_sizes, int n_in,
                              void* d_out, int out_size, void* d_ws, size_t ws_size,
                              hipStream_t stream) {
  const float* condition    = (const float*)d_in[0];
  const float* rel_pos_sig  = (const float*)d_in[1];
  const float* cond_a       = (const float*)d_in[2];
  const float* cond_w       = (const float*)d_in[3];
  const float* cond_b       = (const float*)d_in[4];
  const float* cayley_w     = (const float*)d_in[5];
  const float* lin0_w       = (const float*)d_in[6];
  const float* lin_w        = (const float*)d_in[7];
  const float* silu_a       = (const float*)d_in[8];
  const float* silu_b       = (const float*)d_in[9];
  const float* q_w          = (const float*)d_in[10];
  const float* gp_w         = (const float*)d_in[11];
  const float* final_w      = (const float*)d_in[12];
  const float* shell_sigma  = (const float*)d_in[13];
  float* out = (float*)d_out;
  float* ws  = (float*)d_ws;

  float* norm2 = ws;                       // [NPAD]
  float* hA    = ws + NPAD;                // [8][128][NPAD]
  float* hB    = hA + 8*HID*NPAD;          // [8][128][NPAD]

  k_prep<<<dim3((NPAD+255)/256), 256, 0, stream>>>(condition, rel_pos_sig, cond_a, cond_w, cond_b, norm2, hA);

  const dim3 gl(NT, 4);
  // layer 0 (Kin = 33)
  k_lin_silu<33><<<gl, 256, 0, stream>>>(hA, lin0_w, silu_a + 0*512, silu_b + 0*512, hB);
  k_q_gprod<<<gl, 256, 0, stream>>>(hB, q_w + 0*65536, gp_w + 0*2560, hA);
  // layers 1..3 (Kin = 128)
  for (int l=1; l<4; ++l){
    k_lin_silu<128><<<gl, 256, 0, stream>>>(hA, lin_w + (size_t)(l-1)*65536, silu_a + l*512, silu_b + l*512, hB);
    k_q_gprod<<<gl, 256, 0, stream>>>(hB, q_w + (size_t)l*65536, gp_w + (size_t)l*2560, hA);
  }

  k_final<<<dim3(NT, 64), 256, 0, stream>>>(hA, final_w, shell_sigma, cayley_w, norm2, out);
}

// Round 4
// 834.739 us; speedup vs baseline: 1.3783x; 1.3783x over previous
//
#include <hip/hip_runtime.h>
#include <math.h>

#define NB 8
#define NG 4
#define HID 128
#define NPTS 1331
#define NPAD 1344          // 21 * 64
#define NT 21
#define EPS 1e-6f

// weight arena (float4 units): lt0 [33][128] | lt1..3 [128][128] | qt0..3 [128][128]
#define LT0_F4   (33*128)                 // 4224
#define MAT_F4   (128*128)                // 16384
#define ARENA_F4 (LT0_F4 + 7*MAT_F4)      // 118912

// ---------------- compile-time Clifford algebra tables ----------------
struct Alg {
  int grade[NB];
  signed char gp_j[NB][NB]; float gp_s[NB][NB]; signed char gp_p[NB][NB]; // gprod (i,k)->(j,sign,path)
  signed char ks_k[NB][NB]; float ks_s[NB][NB]; signed char ks_p[NB][NB]; // expand (l,m)->(k*,sign,path)
};

constexpr int popc3(int x){ return (x&1)+((x>>1)&1)+((x>>2)&1); }

constexpr Alg build_alg(){
  Alg A{};
  int order[NB]{}; int idx[NB]{};
  int t=0;
  for(int g=0; g<=3; ++g) for(int b=0;b<NB;++b) if(popc3(b)==g) order[t++]=b;
  for(int i=0;i<NB;++i) idx[order[i]]=i;
  for(int i=0;i<NB;++i) A.grade[i]=popc3(order[i]);
  float C[NB][NB][NB]{};
  for(int a=0;a<NB;++a) for(int b=0;b<NB;++b){
    int s=0, tt=a>>1;
    while(tt){ s += popc3(tt&b); tt>>=1; }
    C[idx[a]][idx[b]][idx[a^b]] = (s&1)?-1.0f:1.0f;
  }
  bool paths[NG][NG][NG]{};
  for(int i=0;i<NB;++i)for(int j=0;j<NB;++j)for(int k=0;k<NB;++k)
    if(C[i][j][k]!=0.0f) paths[A.grade[i]][A.grade[j]][A.grade[k]]=true;
  int pid[NG][NG][NG]{};
  int p=0;
  for(int a=0;a<NG;++a)for(int b=0;b<NG;++b)for(int c=0;c<NG;++c)
    if(paths[a][b][c]) pid[a][b][c]=p++;
  for(int i=0;i<NB;++i)for(int k=0;k<NB;++k){
    int j = idx[order[i]^order[k]];
    A.gp_j[i][k]=(signed char)j;
    A.gp_s[i][k]=C[i][k][j];
    A.gp_p[i][k]=(signed char)pid[A.grade[i]][A.grade[k]][A.grade[j]];
  }
  for(int l=0;l<NB;++l)for(int m=0;m<NB;++m){
    int k = idx[order[l]^order[m]];
    A.ks_k[l][m]=(signed char)k;
    A.ks_s[l][m]=C[k][m][l];
    A.ks_p[l][m]=(signed char)pid[A.grade[k]][A.grade[m]][A.grade[l]];
  }
  return A;
}

__device__ const Alg ALG = build_alg();

__device__ __forceinline__ float sigm(float x){ return 1.f/(1.f+expf(-x)); }

// ---------------- KT: transpose weights [o][i][4] -> [i][o][4] ----------------
__global__ __launch_bounds__(256) void k_tw(
    const float4* __restrict__ lin0_w,  // [128][33]
    const float4* __restrict__ lin_w,   // [3][128][128]
    const float4* __restrict__ q_w,     // [4][128][128]
    float4* __restrict__ wt)            // arena
{
  const int t = blockIdx.x*256 + threadIdx.x;
  if (t >= ARENA_F4) return;
  if (t < LT0_F4){
    const int i = t >> 7, o = t & 127;
    wt[t] = lin0_w[o*33 + i];
  } else {
    const int t2 = t - LT0_F4;
    const int mi = t2 >> 14;            // 0..6
    const int loc = t2 & 16383;
    const int i = loc >> 7, o = loc & 127;
    const float4 v = (mi < 3) ? lin_w[mi*MAT_F4 + o*128 + i]
                              : q_w[(mi-3)*MAT_F4 + o*128 + i];
    wt[t] = v;
  }
}

// ---------------- K0: grid + conditioning -> h0 [8][128][NPAD] (ch 0..32) ----
__global__ __launch_bounds__(256) void k_prep(
    const float* __restrict__ condition,  // [32][8]
    const float* __restrict__ sigma1,     // [1]
    const float* __restrict__ cond_a,     // [32][4]
    const float* __restrict__ cond_w,     // [4][128]
    const float* __restrict__ cond_b,     // [128]
    float* __restrict__ norm2_o,          // [NPAD]
    float* __restrict__ h0)               // [8][128][NPAD]
{
  const int n = blockIdx.x*256 + threadIdx.x;
  if (n >= NPAD) return;
  const bool act = (n < NPTS);
  float px=0.f, py=0.f, pz=0.f, nr=0.f, sc=0.f;
  if (act){
    int i0 = n/121; int r = n - i0*121; int i1 = r/11; int i2 = r - i1*11;
    px = (float)(-1.0 + 0.2*(double)i0);
    py = (float)(-1.0 + 0.2*(double)i1);
    pz = (float)(-1.0 + 0.2*(double)i2);
    nr = px*px + py*py + pz*pz;
    float s = sigma1[0];
    sc = expf(-nr/(2.f*s*s));
  }
  norm2_o[n] = nr;
  h0[(0*HID+0)*NPAD+n] = sc;
  h0[(1*HID+0)*NPAD+n] = px;
  h0[(2*HID+0)*NPAD+n] = py;
  h0[(3*HID+0)*NPAD+n] = pz;
  h0[(4*HID+0)*NPAD+n] = 0.f;
  h0[(5*HID+0)*NPAD+n] = 0.f;
  h0[(6*HID+0)*NPAD+n] = 0.f;
  h0[(7*HID+0)*NPAD+n] = 0.f;
  const float rn0 = sqrtf(sc*sc + EPS);
  const float rn1 = sqrtf(nr + EPS);
  const float rn2 = sqrtf(EPS);
  const float rn3 = sqrtf(EPS);
  for (int c=0;c<32;++c){
    float cb[NB];
    #pragma unroll
    for (int b=0;b<NB;++b) cb[b] = condition[c*8+b];
    float gn2[4];
    gn2[0] = cb[0]*cb[0] + EPS;
    gn2[1] = cb[1]*cb[1] + cb[2]*cb[2] + cb[3]*cb[3] + EPS;
    gn2[2] = cb[4]*cb[4] + cb[5]*cb[5] + cb[6]*cb[6] + EPS;
    gn2[3] = cb[7]*cb[7] + EPS;
    float fac[4];
    #pragma unroll
    for (int g=0; g<4; ++g){
      const float gn = sqrtf(gn2[g]);
      const float den = fmaf(sigm(cond_a[c*4+g]), gn-1.f, 1.f);
      float scl = cond_b[c*4+g];
      scl = fmaf(rn0, cond_w[0*128 + c*4+g], scl);
      scl = fmaf(rn1, cond_w[1*128 + c*4+g], scl);
      scl = fmaf(rn2, cond_w[2*128 + c*4+g], scl);
      scl = fmaf(rn3, cond_w[3*128 + c*4+g], scl);
      fac[g] = (1.f + scl)/den;
    }
    h0[(0*HID + c+1)*NPAD + n] = act ? cb[0]*fac[0] : 0.f;
    h0[(1*HID + c+1)*NPAD + n] = act ? cb[1]*fac[1] : 0.f;
    h0[(2*HID + c+1)*NPAD + n] = act ? cb[2]*fac[1] : 0.f;
    h0[(3*HID + c+1)*NPAD + n] = act ? cb[3]*fac[1] : 0.f;
    h0[(4*HID + c+1)*NPAD + n] = act ? cb[4]*fac[2] : 0.f;
    h0[(5*HID + c+1)*NPAD + n] = act ? cb[5]*fac[2] : 0.f;
    h0[(6*HID + c+1)*NPAD + n] = act ? cb[6]*fac[2] : 0.f;
    h0[(7*HID + c+1)*NPAD + n] = act ? cb[7]*fac[3] : 0.f;
  }
}

// ---------------- KM: fused 4-layer Clifford MLP (per-point in LDS) ----------
// block = 512 thr = 8 waves; wave w owns point n = blk*8 + w.
// LDS h: [8 pts][128 ch][12] (pad 12 -> float4-aligned rows, broadcast reads)
__global__ __launch_bounds__(512) void k_mlp(
    float* __restrict__ hG,             // in: h0 (ch<33) / out: final h, [8][128][NPAD]
    const float4* __restrict__ wt,      // arena
    const float* __restrict__ silu_a,   // [4][128][4]
    const float* __restrict__ silu_b,   // [4][128][4]
    const float* __restrict__ gp_w)     // [4][128][20]
{
  __shared__ float hl[8][HID][12];
  const int lane = threadIdx.x & 63;
  const int wv   = threadIdx.x >> 6;
  const int n    = blockIdx.x*8 + wv;
  const int c0 = lane, c1 = lane + 64;

  // stage h0 (channels 0..32) into LDS
  if (lane < 33){
    #pragma unroll
    for (int b=0;b<NB;++b) hl[wv][lane][b] = hG[(b*HID+lane)*NPAD + n];
  }
  __syncthreads();

  for (int l=0; l<4; ++l){
    const int kin = l ? HID : 33;
    const float4* Wl = l ? (wt + LT0_F4 + (size_t)(l-1)*MAT_F4) : wt;
    const float4* Ql = wt + LT0_F4 + 3*MAT_F4 + (size_t)l*MAT_F4;
    const float* sa = silu_a + l*512;
    const float* sb = silu_b + l*512;
    const float* gw = gp_w  + l*2560;

    // ---- lin: a = W h ----
    float a0[NB] = {0,0,0,0,0,0,0,0};
    float a1[NB] = {0,0,0,0,0,0,0,0};
    for (int i=0;i<kin;++i){
      const float4 hx = *reinterpret_cast<const float4*>(&hl[wv][i][0]);
      const float4 hy = *reinterpret_cast<const float4*>(&hl[wv][i][4]);
      const float4 w0 = Wl[i*HID + c0];
      const float4 w1 = Wl[i*HID + c1];
      a0[0]=fmaf(hx.x,w0.x,a0[0]); a0[1]=fmaf(hx.y,w0.y,a0[1]);
      a0[2]=fmaf(hx.z,w0.y,a0[2]); a0[3]=fmaf(hx.w,w0.y,a0[3]);
      a0[4]=fmaf(hy.x,w0.z,a0[4]); a0[5]=fmaf(hy.y,w0.z,a0[5]);
      a0[6]=fmaf(hy.z,w0.z,a0[6]); a0[7]=fmaf(hy.w,w0.w,a0[7]);
      a1[0]=fmaf(hx.x,w1.x,a1[0]); a1[1]=fmaf(hx.y,w1.y,a1[1]);
      a1[2]=fmaf(hx.z,w1.y,a1[2]); a1[3]=fmaf(hx.w,w1.y,a1[3]);
      a1[4]=fmaf(hy.x,w1.z,a1[4]); a1[5]=fmaf(hy.y,w1.z,a1[5]);
      a1[6]=fmaf(hy.z,w1.z,a1[6]); a1[7]=fmaf(hy.w,w1.w,a1[7]);
    }
    // ---- silu ----
    {
      const float g0 = sqrtf(a0[0]*a0[0] + EPS);
      const float g1 = sqrtf(a0[1]*a0[1] + a0[2]*a0[2] + a0[3]*a0[3] + EPS);
      const float g2 = sqrtf(a0[4]*a0[4] + a0[5]*a0[5] + a0[6]*a0[6] + EPS);
      const float g3 = sqrtf(a0[7]*a0[7] + EPS);
      const float t0 = sigm(fmaf(sa[c0*4+0], g0, sb[c0*4+0]));
      const float t1 = sigm(fmaf(sa[c0*4+1], g1, sb[c0*4+1]));
      const float t2 = sigm(fmaf(sa[c0*4+2], g2, sb[c0*4+2]));
      const float t3 = sigm(fmaf(sa[c0*4+3], g3, sb[c0*4+3]));
      a0[0]*=t0; a0[1]*=t1; a0[2]*=t1; a0[3]*=t1; a0[4]*=t2; a0[5]*=t2; a0[6]*=t2; a0[7]*=t3;
    }
    {
      const float g0 = sqrtf(a1[0]*a1[0] + EPS);
      const float g1 = sqrtf(a1[1]*a1[1] + a1[2]*a1[2] + a1[3]*a1[3] + EPS);
      const float g2 = sqrtf(a1[4]*a1[4] + a1[5]*a1[5] + a1[6]*a1[6] + EPS);
      const float g3 = sqrtf(a1[7]*a1[7] + EPS);
      const float t0 = sigm(fmaf(sa[c1*4+0], g0, sb[c1*4+0]));
      const float t1 = sigm(fmaf(sa[c1*4+1], g1, sb[c1*4+1]));
      const float t2 = sigm(fmaf(sa[c1*4+2], g2, sb[c1*4+2]));
      const float t3 = sigm(fmaf(sa[c1*4+3], g3, sb[c1*4+3]));
      a1[0]*=t0; a1[1]*=t1; a1[2]*=t1; a1[3]*=t1; a1[4]*=t2; a1[5]*=t2; a1[6]*=t2; a1[7]*=t3;
    }
    __syncthreads();
    #pragma unroll
    for (int b=0;b<NB;++b){ hl[wv][c0][b]=a0[b]; hl[wv][c1][b]=a1[b]; }
    __syncthreads();

    // ---- q = Q h' ----
    float q0[NB] = {0,0,0,0,0,0,0,0};
    float q1[NB] = {0,0,0,0,0,0,0,0};
    for (int i=0;i<HID;++i){
      const float4 hx = *reinterpret_cast<const float4*>(&hl[wv][i][0]);
      const float4 hy = *reinterpret_cast<const float4*>(&hl[wv][i][4]);
      const float4 w0 = Ql[i*HID + c0];
      const float4 w1 = Ql[i*HID + c1];
      q0[0]=fmaf(hx.x,w0.x,q0[0]); q0[1]=fmaf(hx.y,w0.y,q0[1]);
      q0[2]=fmaf(hx.z,w0.y,q0[2]); q0[3]=fmaf(hx.w,w0.y,q0[3]);
      q0[4]=fmaf(hy.x,w0.z,q0[4]); q0[5]=fmaf(hy.y,w0.z,q0[5]);
      q0[6]=fmaf(hy.z,w0.z,q0[6]); q0[7]=fmaf(hy.w,w0.w,q0[7]);
      q1[0]=fmaf(hx.x,w1.x,q1[0]); q1[1]=fmaf(hx.y,w1.y,q1[1]);
      q1[2]=fmaf(hx.z,w1.y,q1[2]); q1[3]=fmaf(hx.w,w1.y,q1[3]);
      q1[4]=fmaf(hy.x,w1.z,q1[4]); q1[5]=fmaf(hy.y,w1.z,q1[5]);
      q1[6]=fmaf(hy.z,w1.z,q1[6]); q1[7]=fmaf(hy.w,w1.w,q1[7]);
    }
    // ---- gprod: ov = x *_{gw} q ----
    float x0[NB], x1[NB];
    #pragma unroll
    for (int b=0;b<NB;++b){ x0[b]=hl[wv][c0][b]; x1[b]=hl[wv][c1][b]; }
    float wp0[20], wp1[20];
    #pragma unroll
    for (int p5=0;p5<5;++p5){
      const float4 v0 = *reinterpret_cast<const float4*>(gw + c0*20 + p5*4);
      const float4 v1 = *reinterpret_cast<const float4*>(gw + c1*20 + p5*4);
      wp0[p5*4+0]=v0.x; wp0[p5*4+1]=v0.y; wp0[p5*4+2]=v0.z; wp0[p5*4+3]=v0.w;
      wp1[p5*4+0]=v1.x; wp1[p5*4+1]=v1.y; wp1[p5*4+2]=v1.z; wp1[p5*4+3]=v1.w;
    }
    float o0[NB] = {0,0,0,0,0,0,0,0};
    float o1[NB] = {0,0,0,0,0,0,0,0};
    #pragma unroll
    for (int i=0;i<NB;++i)
      #pragma unroll
      for (int k=0;k<NB;++k){
        const int J = ALG.gp_j[i][k];
        const int P = ALG.gp_p[i][k];
        const float t0v = x0[i]*q0[k];
        const float t1v = x1[i]*q1[k];
        o0[J] = fmaf(ALG.gp_s[i][k] > 0.f ? t0v : -t0v, wp0[P], o0[J]);
        o1[J] = fmaf(ALG.gp_s[i][k] > 0.f ? t1v : -t1v, wp1[P], o1[J]);
      }
    __syncthreads();
    #pragma unroll
    for (int b=0;b<NB;++b){ hl[wv][c0][b]=o0[b]; hl[wv][c1][b]=o1[b]; }
    __syncthreads();
  }

  // writeback to global [b][ch][NPAD] (32B-contiguous chunks over the 8 pts)
  #pragma unroll
  for (int rep=0; rep<16; ++rep){
    const int e  = rep*512 + threadIdx.x;
    const int pt = e & 7;
    const int b  = (e>>3) & 7;
    const int ch = e >> 6;
    hG[(b*HID+ch)*NPAD + blockIdx.x*8 + pt] = hl[pt][ch][b];
  }
}

// ---------------- KF: final mvlinear + shell + Cayley expansion --------------
__global__ __launch_bounds__(256) void k_final(
    const float* __restrict__ hin,   // [8][128][NPAD]
    const float* __restrict__ fw,    // [1024][128][4]
    const float* __restrict__ ss,    // [1024][8]
    const float* __restrict__ cw,    // [32][32][20]
    const float* __restrict__ norm2, // [NPAD]
    float* __restrict__ out)         // [256][256][1331]
{
  __shared__ float lds[256*64];      // [8 blades][32 ch][64 n] = 64 KiB
  const int lane = threadIdx.x & 63;
  const int wv   = threadIdx.x >> 6;
  const int nb   = blockIdx.x;                 // 0..20
  const int n    = nb*64 + lane;
  const int oi0  = blockIdx.y * 16 + wv * 4;   // 4 oi per thread
  float acc[4][NB];
  #pragma unroll
  for (int j=0;j<4;++j)
    #pragma unroll
    for (int b=0;b<NB;++b) acc[j][b]=0.f;

  for (int ci=0; ci<HID; ci+=32){
    __syncthreads();
    #pragma unroll
    for (int rep=0; rep<16; ++rep){
      const int e   = rep*256 + threadIdx.x;   // float4 id, 4096 total
      const int row = e >> 4;                  // (b*32 + cc)
      const int c4  = e & 15;
      const int b   = row >> 5;
      const int cc  = row & 31;
      const float4 v = *reinterpret_cast<const float4*>(hin + (size_t)(b*HID + ci + cc)*NPAD + nb*64 + c4*4);
      *reinterpret_cast<float4*>(&lds[row*64 + c4*4]) = v;
    }
    __syncthreads();
    for (int cc=0; cc<32; ++cc){
      float hv[NB];
      #pragma unroll
      for (int b=0;b<NB;++b) hv[b] = lds[(b*32+cc)*64 + lane];
      #pragma unroll
      for (int j=0;j<4;++j){
        const float4 w = *reinterpret_cast<const float4*>(fw + ((size_t)(oi0+j)*HID + ci+cc)*4);
        acc[j][0] = fmaf(hv[0], w.x, acc[j][0]);
        acc[j][1] = fmaf(hv[1], w.y, acc[j][1]);
        acc[j][2] = fmaf(hv[2], w.y, acc[j][2]);
        acc[j][3] = fmaf(hv[3], w.y, acc[j][3]);
        acc[j][4] = fmaf(hv[4], w.z, acc[j][4]);
        acc[j][5] = fmaf(hv[5], w.z, acc[j][5]);
        acc[j][6] = fmaf(hv[6], w.z, acc[j][6]);
        acc[j][7] = fmaf(hv[7], w.w, acc[j][7]);
      }
    }
  }

  const float INVS = (float)(1.0 / sqrt((double)NPTS));
  const float nr   = norm2[n];
  const bool  act  = (n < NPTS);
  #pragma unroll
  for (int j=0;j<4;++j){
    const int oi = oi0+j;
    const int o  = oi >> 5;
    const int i  = oi & 31;
    float kf[NB];
    #pragma unroll
    for (int b=0;b<NB;++b){
      const float s = ss[oi*8+b];
      kf[b] = acc[j][b] * expf(-nr/(2.f*s*s)) * INVS;
    }
    float wp[20];
    #pragma unroll
    for (int p=0;p<20;++p) wp[p] = cw[oi*20+p];
    float* obase = out + (size_t)(o*2048 + i*8)*NPTS + n;
    if (act){
      #pragma unroll
      for (int l=0;l<NB;++l)
        #pragma unroll
        for (int m=0;m<NB;++m){
          const float t = kf[ALG.ks_k[l][m]] * wp[ALG.ks_p[l][m]];
          obase[(size_t)(l*256+m)*NPTS] = (ALG.ks_s[l][m] > 0.f) ? t : -t;
        }
    }
  }
}

// ---------------- launch ----------------
extern "C" void kernel_launch(void* const* d_in, const int* in_sizes, int n_in,
                              void* d_out, int out_size, void* d_ws, size_t ws_size,
                              hipStream_t stream) {
  const float* condition    = (const float*)d_in[0];
  const float* rel_pos_sig  = (const float*)d_in[1];
  const float* cond_a       = (const float*)d_in[2];
  const float* cond_w       = (const float*)d_in[3];
  const float* cond_b       = (const float*)d_in[4];
  const float* cayley_w     = (const float*)d_in[5];
  const float* lin0_w       = (const float*)d_in[6];
  const float* lin_w        = (const float*)d_in[7];
  const float* silu_a       = (const float*)d_in[8];
  const float* silu_b       = (const float*)d_in[9];
  const float* q_w          = (const float*)d_in[10];
  const float* gp_w         = (const float*)d_in[11];
  const float* final_w      = (const float*)d_in[12];
  const float* shell_sigma  = (const float*)d_in[13];
  float* out = (float*)d_out;
  float* ws  = (float*)d_ws;

  float*  norm2 = ws;                       // [NPAD]
  float*  hA    = ws + NPAD;                // [8][128][NPAD]
  float4* arena = (float4*)(hA + 8*HID*NPAD);

  k_tw<<<dim3((ARENA_F4+255)/256), 256, 0, stream>>>(
      (const float4*)lin0_w, (const float4*)lin_w, (const float4*)q_w, arena);

  k_prep<<<dim3((NPAD+255)/256), 256, 0, stream>>>(
      condition, rel_pos_sig, cond_a, cond_w, cond_b, norm2, hA);

  k_mlp<<<dim3(NPAD/8), 512, 0, stream>>>(hA, arena, silu_a, silu_b, gp_w);

  k_final<<<dim3(NT, 64), 256, 0, stream>>>(hA, final_w, shell_sigma, cayley_w, norm2, out);
}

// Round 5
// 744.589 us; speedup vs baseline: 1.5452x; 1.1211x over previous
//
#include <hip/hip_runtime.h>
#include <math.h>

#define NB 8
#define NG 4
#define HID 128
#define NPTS 1331
#define NPAD 1344          // 21 * 64
#define NT 21
#define EPS 1e-6f

// weight arena (float4 units): lt0 [33][128] | lt1..3 [128][128] | qt0..3 [128][128]
#define LT0_F4   (33*128)                 // 4224
#define MAT_F4   (128*128)                // 16384
#define ARENA_F4 (LT0_F4 + 7*MAT_F4)      // 118912

// ---------------- compile-time Clifford algebra tables ----------------
struct Alg {
  int grade[NB];
  signed char gp_j[NB][NB]; float gp_s[NB][NB]; signed char gp_p[NB][NB]; // gprod (i,k)->(j,sign,path)
  signed char ks_k[NB][NB]; float ks_s[NB][NB]; signed char ks_p[NB][NB]; // expand (l,m)->(k*,sign,path)
};

constexpr int popc3(int x){ return (x&1)+((x>>1)&1)+((x>>2)&1); }

constexpr Alg build_alg(){
  Alg A{};
  int order[NB]{}; int idx[NB]{};
  int t=0;
  for(int g=0; g<=3; ++g) for(int b=0;b<NB;++b) if(popc3(b)==g) order[t++]=b;
  for(int i=0;i<NB;++i) idx[order[i]]=i;
  for(int i=0;i<NB;++i) A.grade[i]=popc3(order[i]);
  float C[NB][NB][NB]{};
  for(int a=0;a<NB;++a) for(int b=0;b<NB;++b){
    int s=0, tt=a>>1;
    while(tt){ s += popc3(tt&b); tt>>=1; }
    C[idx[a]][idx[b]][idx[a^b]] = (s&1)?-1.0f:1.0f;
  }
  bool paths[NG][NG][NG]{};
  for(int i=0;i<NB;++i)for(int j=0;j<NB;++j)for(int k=0;k<NB;++k)
    if(C[i][j][k]!=0.0f) paths[A.grade[i]][A.grade[j]][A.grade[k]]=true;
  int pid[NG][NG][NG]{};
  int p=0;
  for(int a=0;a<NG;++a)for(int b=0;b<NG;++b)for(int c=0;c<NG;++c)
    if(paths[a][b][c]) pid[a][b][c]=p++;
  for(int i=0;i<NB;++i)for(int k=0;k<NB;++k){
    int j = idx[order[i]^order[k]];
    A.gp_j[i][k]=(signed char)j;
    A.gp_s[i][k]=C[i][k][j];
    A.gp_p[i][k]=(signed char)pid[A.grade[i]][A.grade[k]][A.grade[j]];
  }
  for(int l=0;l<NB;++l)for(int m=0;m<NB;++m){
    int k = idx[order[l]^order[m]];
    A.ks_k[l][m]=(signed char)k;
    A.ks_s[l][m]=C[k][m][l];
    A.ks_p[l][m]=(signed char)pid[A.grade[k]][A.grade[m]][A.grade[l]];
  }
  return A;
}

__device__ const Alg ALG = build_alg();

__device__ __forceinline__ float sigm(float x){ return 1.f/(1.f+expf(-x)); }

// ---------------- KT: transpose weights [o][i][4] -> [i][o][4] ----------------
__global__ __launch_bounds__(256) void k_tw(
    const float4* __restrict__ lin0_w,  // [128][33]
    const float4* __restrict__ lin_w,   // [3][128][128]
    const float4* __restrict__ q_w,     // [4][128][128]
    float4* __restrict__ wt)            // arena
{
  const int t = blockIdx.x*256 + threadIdx.x;
  if (t >= ARENA_F4) return;
  if (t < LT0_F4){
    const int i = t >> 7, o = t & 127;
    wt[t] = lin0_w[o*33 + i];
  } else {
    const int t2 = t - LT0_F4;
    const int mi = t2 >> 14;            // 0..6
    const int loc = t2 & 16383;
    const int i = loc >> 7, o = loc & 127;
    const float4 v = (mi < 3) ? lin_w[mi*MAT_F4 + o*128 + i]
                              : q_w[(mi-3)*MAT_F4 + o*128 + i];
    wt[t] = v;
  }
}

// ---------------- K0: grid + conditioning -> h0 [8][128][NPAD] (ch 0..32) ----
__global__ __launch_bounds__(256) void k_prep(
    const float* __restrict__ condition,  // [32][8]
    const float* __restrict__ sigma1,     // [1]
    const float* __restrict__ cond_a,     // [32][4]
    const float* __restrict__ cond_w,     // [4][128]
    const float* __restrict__ cond_b,     // [128]
    float* __restrict__ norm2_o,          // [NPAD]
    float* __restrict__ h0)               // [8][128][NPAD]
{
  const int n = blockIdx.x*256 + threadIdx.x;
  if (n >= NPAD) return;
  const bool act = (n < NPTS);
  float px=0.f, py=0.f, pz=0.f, nr=0.f, sc=0.f;
  if (act){
    int i0 = n/121; int r = n - i0*121; int i1 = r/11; int i2 = r - i1*11;
    px = (float)(-1.0 + 0.2*(double)i0);
    py = (float)(-1.0 + 0.2*(double)i1);
    pz = (float)(-1.0 + 0.2*(double)i2);
    nr = px*px + py*py + pz*pz;
    float s = sigma1[0];
    sc = expf(-nr/(2.f*s*s));
  }
  norm2_o[n] = nr;
  h0[(0*HID+0)*NPAD+n] = sc;
  h0[(1*HID+0)*NPAD+n] = px;
  h0[(2*HID+0)*NPAD+n] = py;
  h0[(3*HID+0)*NPAD+n] = pz;
  h0[(4*HID+0)*NPAD+n] = 0.f;
  h0[(5*HID+0)*NPAD+n] = 0.f;
  h0[(6*HID+0)*NPAD+n] = 0.f;
  h0[(7*HID+0)*NPAD+n] = 0.f;
  const float rn0 = sqrtf(sc*sc + EPS);
  const float rn1 = sqrtf(nr + EPS);
  const float rn2 = sqrtf(EPS);
  const float rn3 = sqrtf(EPS);
  for (int c=0;c<32;++c){
    float cb[NB];
    #pragma unroll
    for (int b=0;b<NB;++b) cb[b] = condition[c*8+b];
    float gn2[4];
    gn2[0] = cb[0]*cb[0] + EPS;
    gn2[1] = cb[1]*cb[1] + cb[2]*cb[2] + cb[3]*cb[3] + EPS;
    gn2[2] = cb[4]*cb[4] + cb[5]*cb[5] + cb[6]*cb[6] + EPS;
    gn2[3] = cb[7]*cb[7] + EPS;
    float fac[4];
    #pragma unroll
    for (int g=0; g<4; ++g){
      const float gn = sqrtf(gn2[g]);
      const float den = fmaf(sigm(cond_a[c*4+g]), gn-1.f, 1.f);
      float scl = cond_b[c*4+g];
      scl = fmaf(rn0, cond_w[0*128 + c*4+g], scl);
      scl = fmaf(rn1, cond_w[1*128 + c*4+g], scl);
      scl = fmaf(rn2, cond_w[2*128 + c*4+g], scl);
      scl = fmaf(rn3, cond_w[3*128 + c*4+g], scl);
      fac[g] = (1.f + scl)/den;
    }
    h0[(0*HID + c+1)*NPAD + n] = act ? cb[0]*fac[0] : 0.f;
    h0[(1*HID + c+1)*NPAD + n] = act ? cb[1]*fac[1] : 0.f;
    h0[(2*HID + c+1)*NPAD + n] = act ? cb[2]*fac[1] : 0.f;
    h0[(3*HID + c+1)*NPAD + n] = act ? cb[3]*fac[1] : 0.f;
    h0[(4*HID + c+1)*NPAD + n] = act ? cb[4]*fac[2] : 0.f;
    h0[(5*HID + c+1)*NPAD + n] = act ? cb[5]*fac[2] : 0.f;
    h0[(6*HID + c+1)*NPAD + n] = act ? cb[6]*fac[2] : 0.f;
    h0[(7*HID + c+1)*NPAD + n] = act ? cb[7]*fac[3] : 0.f;
  }
}

// ---------------- MLP helpers ----------------
template<int KIN>
__device__ __forceinline__ void matvec2(const float* hw, const float4* __restrict__ W,
                                        int c0, int c1, float a0[NB], float a1[NB])
{
  #pragma unroll
  for (int b=0;b<NB;++b){ a0[b]=0.f; a1[b]=0.f; }
  #pragma unroll 4
  for (int i=0;i<KIN;++i){
    const float4 hx = *reinterpret_cast<const float4*>(hw + i*12);
    const float4 hy = *reinterpret_cast<const float4*>(hw + i*12 + 4);
    const float4 w0 = W[i*HID + c0];
    const float4 w1 = W[i*HID + c1];
    a0[0]=fmaf(hx.x,w0.x,a0[0]); a0[1]=fmaf(hx.y,w0.y,a0[1]);
    a0[2]=fmaf(hx.z,w0.y,a0[2]); a0[3]=fmaf(hx.w,w0.y,a0[3]);
    a0[4]=fmaf(hy.x,w0.z,a0[4]); a0[5]=fmaf(hy.y,w0.z,a0[5]);
    a0[6]=fmaf(hy.z,w0.z,a0[6]); a0[7]=fmaf(hy.w,w0.w,a0[7]);
    a1[0]=fmaf(hx.x,w1.x,a1[0]); a1[1]=fmaf(hx.y,w1.y,a1[1]);
    a1[2]=fmaf(hx.z,w1.y,a1[2]); a1[3]=fmaf(hx.w,w1.y,a1[3]);
    a1[4]=fmaf(hy.x,w1.z,a1[4]); a1[5]=fmaf(hy.y,w1.z,a1[5]);
    a1[6]=fmaf(hy.z,w1.z,a1[6]); a1[7]=fmaf(hy.w,w1.w,a1[7]);
  }
}

__device__ __forceinline__ void silu8(float a[NB], const float* sa, const float* sb)
{
  const float g0 = sqrtf(a[0]*a[0] + EPS);
  const float g1 = sqrtf(a[1]*a[1] + a[2]*a[2] + a[3]*a[3] + EPS);
  const float g2 = sqrtf(a[4]*a[4] + a[5]*a[5] + a[6]*a[6] + EPS);
  const float g3 = sqrtf(a[7]*a[7] + EPS);
  const float t0 = sigm(fmaf(sa[0], g0, sb[0]));
  const float t1 = sigm(fmaf(sa[1], g1, sb[1]));
  const float t2 = sigm(fmaf(sa[2], g2, sb[2]));
  const float t3 = sigm(fmaf(sa[3], g3, sb[3]));
  a[0]*=t0; a[1]*=t1; a[2]*=t1; a[3]*=t1; a[4]*=t2; a[5]*=t2; a[6]*=t2; a[7]*=t3;
}

__device__ __forceinline__ void store_row(float* hw, int c, const float a[NB])
{
  float4 v0 = {a[0],a[1],a[2],a[3]};
  float4 v1 = {a[4],a[5],a[6],a[7]};
  *reinterpret_cast<float4*>(hw + c*12)     = v0;
  *reinterpret_cast<float4*>(hw + c*12 + 4) = v1;
}

__device__ __forceinline__ void gprod8(const float x[NB], const float q[NB],
                                       const float wp[20], float o[NB])
{
  #pragma unroll
  for (int b=0;b<NB;++b) o[b]=0.f;
  #pragma unroll
  for (int i=0;i<NB;++i)
    #pragma unroll
    for (int k=0;k<NB;++k){
      const int J = ALG.gp_j[i][k];
      const int P = ALG.gp_p[i][k];
      const float t = x[i]*q[k];
      o[J] = fmaf(ALG.gp_s[i][k] > 0.f ? t : -t, wp[P], o[J]);
    }
}

// ---------------- KM: fused 4-layer Clifford MLP, barrier-free layers -------
// block = 512 thr = 8 waves; wave w owns point n = blk*8 + w; LDS slice wave-private.
__global__ __launch_bounds__(512) void k_mlp(
    float* __restrict__ hG,             // in: h0 (ch<33) / out: final h, [8][128][NPAD]
    const float4* __restrict__ wt,      // arena
    const float* __restrict__ silu_a,   // [4][128][4]
    const float* __restrict__ silu_b,   // [4][128][4]
    const float* __restrict__ gp_w)     // [4][128][20]
{
  __shared__ float hl[8][HID][12];
  const int lane = threadIdx.x & 63;
  const int wv   = threadIdx.x >> 6;
  const int n    = blockIdx.x*8 + wv;
  const int c0 = lane, c1 = lane + 64;
  float* hw = &hl[wv][0][0];           // wave-private LDS slice

  // stage h0 (channels 0..32) into LDS — intra-wave, no barrier needed
  if (lane < 33){
    #pragma unroll
    for (int b=0;b<NB;++b) hw[lane*12+b] = hG[(b*HID+lane)*NPAD + n];
  }

  float a0[NB], a1[NB], q0[NB], q1[NB], o0[NB], o1[NB];
  float wp0[20], wp1[20];

  #pragma unroll 1
  for (int l=0; l<4; ++l){
    const float4* Ql = wt + LT0_F4 + 3*MAT_F4 + (size_t)l*MAT_F4;
    const float* sa = silu_a + l*512;
    const float* sb = silu_b + l*512;
    const float* gw = gp_w  + l*2560;

    // ---- lin + silu ----
    if (l == 0) matvec2<33>(hw, wt, c0, c1, a0, a1);
    else        matvec2<HID>(hw, wt + LT0_F4 + (size_t)(l-1)*MAT_F4, c0, c1, a0, a1);
    silu8(a0, sa + c0*4, sb + c0*4);
    silu8(a1, sa + c1*4, sb + c1*4);
    store_row(hw, c0, a0);
    store_row(hw, c1, a1);

    // ---- q = Q h' ----
    matvec2<HID>(hw, Ql, c0, c1, q0, q1);

    // ---- gprod (x = silu output, still in regs) ----
    #pragma unroll
    for (int p5=0;p5<5;++p5){
      const float4 v0 = *reinterpret_cast<const float4*>(gw + c0*20 + p5*4);
      const float4 v1 = *reinterpret_cast<const float4*>(gw + c1*20 + p5*4);
      wp0[p5*4+0]=v0.x; wp0[p5*4+1]=v0.y; wp0[p5*4+2]=v0.z; wp0[p5*4+3]=v0.w;
      wp1[p5*4+0]=v1.x; wp1[p5*4+1]=v1.y; wp1[p5*4+2]=v1.z; wp1[p5*4+3]=v1.w;
    }
    gprod8(a0, q0, wp0, o0);
    gprod8(a1, q1, wp1, o1);
    store_row(hw, c0, o0);
    store_row(hw, c1, o1);
  }

  // transposed writeback reads other waves' slices -> one barrier
  __syncthreads();
  #pragma unroll
  for (int rep=0; rep<16; ++rep){
    const int e  = rep*512 + threadIdx.x;
    const int pt = e & 7;
    const int b  = (e>>3) & 7;
    const int ch = e >> 6;
    hG[(b*HID+ch)*NPAD + blockIdx.x*8 + pt] = hl[pt][ch][b];
  }
}

// ---------------- K1: final mvlinear + shell -> kf [1024][8][NPAD] ----------
__global__ __launch_bounds__(256) void k_kfield(
    const float* __restrict__ hin,   // [8][128][NPAD]
    const float* __restrict__ fw,    // [1024][128][4]
    const float* __restrict__ ss,    // [1024][8]
    const float* __restrict__ norm2, // [NPAD]
    float* __restrict__ kf)          // [1024][8][NPAD]
{
  __shared__ float lds[256*64];      // [8 blades][32 ch][64 n] = 64 KiB
  const int lane = threadIdx.x & 63;
  const int wv   = threadIdx.x >> 6;
  const int nb   = blockIdx.x;                 // 0..20
  const int n    = nb*64 + lane;
  const int oi0  = blockIdx.y * 16 + wv * 4;   // 4 oi per thread
  float acc[4][NB];
  #pragma unroll
  for (int j=0;j<4;++j)
    #pragma unroll
    for (int b=0;b<NB;++b) acc[j][b]=0.f;

  for (int ci=0; ci<HID; ci+=32){
    __syncthreads();
    #pragma unroll
    for (int rep=0; rep<16; ++rep){
      const int e   = rep*256 + threadIdx.x;   // float4 id, 4096 total
      const int row = e >> 4;                  // (b*32 + cc)
      const int c4  = e & 15;
      const int b   = row >> 5;
      const int cc  = row & 31;
      const float4 v = *reinterpret_cast<const float4*>(hin + (size_t)(b*HID + ci + cc)*NPAD + nb*64 + c4*4);
      *reinterpret_cast<float4*>(&lds[row*64 + c4*4]) = v;
    }
    __syncthreads();
    for (int cc=0; cc<32; ++cc){
      float hv[NB];
      #pragma unroll
      for (int b=0;b<NB;++b) hv[b] = lds[(b*32+cc)*64 + lane];
      #pragma unroll
      for (int j=0;j<4;++j){
        const float4 w = *reinterpret_cast<const float4*>(fw + ((size_t)(oi0+j)*HID + ci+cc)*4);
        acc[j][0] = fmaf(hv[0], w.x, acc[j][0]);
        acc[j][1] = fmaf(hv[1], w.y, acc[j][1]);
        acc[j][2] = fmaf(hv[2], w.y, acc[j][2]);
        acc[j][3] = fmaf(hv[3], w.y, acc[j][3]);
        acc[j][4] = fmaf(hv[4], w.z, acc[j][4]);
        acc[j][5] = fmaf(hv[5], w.z, acc[j][5]);
        acc[j][6] = fmaf(hv[6], w.z, acc[j][6]);
        acc[j][7] = fmaf(hv[7], w.w, acc[j][7]);
      }
    }
  }

  const float INVS = (float)(1.0 / sqrt((double)NPTS));
  const float nr   = norm2[n];
  #pragma unroll
  for (int j=0;j<4;++j){
    const int oi = oi0+j;
    #pragma unroll
    for (int b=0;b<NB;++b){
      const float s = ss[oi*8+b];
      kf[((size_t)oi*8 + b)*NPAD + n] = acc[j][b] * expf(-nr/(2.f*s*s)) * INVS;
    }
  }
}

// ---------------- K2: Cayley expansion, contiguous streaming writes ---------
// 2048 blocks: blk = (o*8+l)*8 + sub; each writes 32 full rows (170 KB contiguous)
__global__ __launch_bounds__(256) void k_expand(
    const float* __restrict__ kf,   // [1024][8][NPAD]
    const float* __restrict__ cw,   // [1024][20]
    float* __restrict__ out)        // [65536][1331]
{
  __shared__ float coef[32][8];
  __shared__ int   km[8];
  const int blk = blockIdx.x;
  const int o   = blk >> 6;
  const int l   = (blk >> 3) & 7;
  const int sub = blk & 7;
  const int t   = threadIdx.x;
  {
    const int i = t >> 3, m = t & 7;
    coef[i][m] = ALG.ks_s[l][m] * cw[(size_t)(o*32+i)*20 + ALG.ks_p[l][m]];
    if (t < 8) km[t] = ALG.ks_k[l][t];
  }
  __syncthreads();

  float* obase = out + ((size_t)((o*8+l)*256 + sub*32)) * NPTS;
  #pragma unroll 1
  for (int rr=0; rr<32; ++rr){
    const int row = sub*32 + rr;
    const int i = row >> 3, m = row & 7;
    const float cf = coef[i][m];
    const float* src = kf + ((size_t)((o*32+i)*8 + km[m])) * NPAD;
    float* dst = obase + (size_t)rr * NPTS;
    #pragma unroll
    for (int base=0; base<6; ++base){
      const int idx = base*256 + t;
      if (idx < NPTS) dst[idx] = cf * src[idx];
    }
  }
}

// ---------------- launch ----------------
extern "C" void kernel_launch(void* const* d_in, const int* in_sizes, int n_in,
                              void* d_out, int out_size, void* d_ws, size_t ws_size,
                              hipStream_t stream) {
  const float* condition    = (const float*)d_in[0];
  const float* rel_pos_sig  = (const float*)d_in[1];
  const float* cond_a       = (const float*)d_in[2];
  const float* cond_w       = (const float*)d_in[3];
  const float* cond_b       = (const float*)d_in[4];
  const float* cayley_w     = (const float*)d_in[5];
  const float* lin0_w       = (const float*)d_in[6];
  const float* lin_w        = (const float*)d_in[7];
  const float* silu_a       = (const float*)d_in[8];
  const float* silu_b       = (const float*)d_in[9];
  const float* q_w          = (const float*)d_in[10];
  const float* gp_w         = (const float*)d_in[11];
  const float* final_w      = (const float*)d_in[12];
  const float* shell_sigma  = (const float*)d_in[13];
  float* out = (float*)d_out;
  float* ws  = (float*)d_ws;

  float*  norm2 = ws;                        // [NPAD]
  float*  hA    = ws + NPAD;                 // [8][128][NPAD]
  float4* arena = (float4*)(hA + 8*HID*NPAD);
  float*  kf    = (float*)(arena + ARENA_F4); // [1024][8][NPAD] = 44 MB

  k_tw<<<dim3((ARENA_F4+255)/256), 256, 0, stream>>>(
      (const float4*)lin0_w, (const float4*)lin_w, (const float4*)q_w, arena);

  k_prep<<<dim3((NPAD+255)/256), 256, 0, stream>>>(
      condition, rel_pos_sig, cond_a, cond_w, cond_b, norm2, hA);

  k_mlp<<<dim3(NPAD/8), 512, 0, stream>>>(hA, arena, silu_a, silu_b, gp_w);

  k_kfield<<<dim3(NT, 64), 256, 0, stream>>>(hA, final_w, shell_sigma, norm2, kf);

  k_expand<<<dim3(2048), 256, 0, stream>>>(kf, cayley_w, out);
}